// Round 1
// baseline (4711.895 us; speedup 1.0000x reference)
//
#include <hip/hip_runtime.h>
#include <cstdint>

// Problem constants (fixed by the reference):
#define H_DIM 4096
#define I_DIM 14336
#define M_TOT 8192   // B*S = 4*2048

typedef __bf16 bf16_t;
typedef bf16_t bf16x8_t __attribute__((ext_vector_type(8)));
typedef float f32x4_t __attribute__((ext_vector_type(4)));

#define AS1 __attribute__((address_space(1)))
#define AS3 __attribute__((address_space(3)))

// fp32 -> bf16 bits, round-to-nearest-even
static __device__ __forceinline__ unsigned short f2bf(float f) {
  union { float f; unsigned int u; } v; v.f = f;
  unsigned int r = ((v.u >> 16) & 1u) + 0x7FFFu;
  return (unsigned short)((v.u + r) >> 16);
}

// async global->LDS, 16B per lane. lds ptr must be wave-uniform; HW writes
// base + lane*16.
static __device__ __forceinline__ void gl2lds16(const void* g, void* l) {
  __builtin_amdgcn_global_load_lds((AS1 void*)(void*)g, (AS3 void*)l, 16, 0, 0);
}

// ---------------------------------------------------------------------------
// Kernel 1: x fp32 -> bf16 (grid-stride, float4 in / ushort4 out)
// ---------------------------------------------------------------------------
__global__ void k_cvt_x(const float* __restrict__ x,
                        unsigned short* __restrict__ xb, long n4) {
  long i = (long)blockIdx.x * blockDim.x + threadIdx.x;
  const long stride = (long)gridDim.x * blockDim.x;
  for (; i < n4; i += stride) {
    float4 v = ((const float4*)x)[i];
    ushort4 o;
    o.x = f2bf(v.x); o.y = f2bf(v.y); o.z = f2bf(v.z); o.w = f2bf(v.w);
    ((ushort4*)xb)[i] = o;
  }
}

// ---------------------------------------------------------------------------
// Kernel 2: dequant + transpose.  w [K][N] int32, s [K/128][N] fp32
//           -> wt [N][K] bf16   (64x64 tile per block, 256 threads)
// ---------------------------------------------------------------------------
__global__ void k_dequant_t(const int* __restrict__ w, const float* __restrict__ s,
                            unsigned short* __restrict__ wt, int K, int N) {
  __shared__ __align__(16) float tile[64 * 68];  // stride 68: f4-aligned, banks ok
  const int n0 = blockIdx.x * 64;
  const int k0 = blockIdx.y * 64;
  const int t = threadIdx.x;
  const int tx = t & 15;   // 16 col-groups of 4
  const int ty = t >> 4;   // 16 rows
#pragma unroll
  for (int i = 0; i < 4; ++i) {
    const long gk = k0 + i * 16 + ty;
    const int4 wv = *(const int4*)(w + gk * N + (n0 + tx * 4));
    const float4 sv = *(const float4*)(s + (gk >> 7) * (long)N + (n0 + tx * 4));
    float4 o;
    o.x = (float)wv.x * sv.x;
    o.y = (float)wv.y * sv.y;
    o.z = (float)wv.z * sv.z;
    o.w = (float)wv.w * sv.w;
    *(float4*)(&tile[(i * 16 + ty) * 68 + tx * 4]) = o;
  }
  __syncthreads();
  // phase 2: thread -> output row n_local = t>>2, k-chunk (t&3)*16
  const int nl = t >> 2;
  const int kc = (t & 3) << 4;
  unsigned int pk[8];
#pragma unroll
  for (int j = 0; j < 8; ++j) {
    unsigned int lo = f2bf(tile[(kc + 2 * j) * 68 + nl]);
    unsigned int hi = f2bf(tile[(kc + 2 * j + 1) * 68 + nl]);
    pk[j] = lo | (hi << 16);
  }
  const long base = (long)(n0 + nl) * K + (k0 + kc);
  uint4* dst = (uint4*)(wt + base);
  dst[0] = make_uint4(pk[0], pk[1], pk[2], pk[3]);
  dst[1] = make_uint4(pk[4], pk[5], pk[6], pk[7]);
}

// ---------------------------------------------------------------------------
// Kernel 3: fused gate/up GEMM + silu.  h = silu(x@W0) * (x@W1), bf16 out.
// BM=128, BN=64, BK=64, 256 threads (2x2 waves, each 64x32, dual acc).
// m97-equivalent resource profile: 32KB LDS, 64 acc regs, 32 MFMA/wave/iter.
// ---------------------------------------------------------------------------
__global__ __launch_bounds__(256) void k_gemm1(
    const unsigned short* __restrict__ xb,   // [M][H]  bf16
    const unsigned short* __restrict__ w0t,  // [I][H]  bf16 (N-major)
    const unsigned short* __restrict__ w1t,  // [I][H]  bf16
    unsigned short* __restrict__ h) {        // [M][I]  bf16
  __shared__ __align__(16) unsigned short sA[128 * 64];
  __shared__ __align__(16) unsigned short sB0[64 * 64];
  __shared__ __align__(16) unsigned short sB1[64 * 64];

  const int Ntiles = I_DIM / 64;  // 224
  const int GROUP = 32;           // m-tiles per group (L2/L3 locality)
  const int id = blockIdx.x;
  const int group = id / (GROUP * Ntiles);
  const int local = id - group * (GROUP * Ntiles);
  const int nt = local / GROUP;
  const int mt = group * GROUP + (local - nt * GROUP);
  const long m0 = (long)mt * 128;
  const long n0 = (long)nt * 64;

  const int t = threadIdx.x;
  const int lane = t & 63;
  const int wave = t >> 6;
  const int wm = wave >> 1;  // 0..1 : 64 rows each
  const int wn = wave & 1;   // 0..1 : 32 cols each

  f32x4_t accg[4][2], accu[4][2];
  const f32x4_t fzero = {0.f, 0.f, 0.f, 0.f};
#pragma unroll
  for (int mi = 0; mi < 4; ++mi)
#pragma unroll
    for (int ni = 0; ni < 2; ++ni) { accg[mi][ni] = fzero; accu[mi][ni] = fzero; }

  // precompute per-thread staging pointers (kt added in loop)
  const unsigned short* ga[4];
#pragma unroll
  for (int i = 0; i < 4; ++i) {
    const int c = i * 256 + wave * 64 + lane;
    ga[i] = xb + (m0 + (c >> 3)) * H_DIM + ((c & 7) << 3);
  }
  const unsigned short* gb0[2];
  const unsigned short* gb1[2];
#pragma unroll
  for (int i = 0; i < 2; ++i) {
    const int c = i * 256 + wave * 64 + lane;
    const long roff = (n0 + (c >> 3)) * (long)H_DIM + ((c & 7) << 3);
    gb0[i] = w0t + roff;
    gb1[i] = w1t + roff;
  }

  for (int kt = 0; kt < H_DIM; kt += 64) {
#pragma unroll
    for (int i = 0; i < 4; ++i)
      gl2lds16(ga[i] + kt, &sA[(i * 256 + wave * 64) * 8]);
#pragma unroll
    for (int i = 0; i < 2; ++i) {
      gl2lds16(gb0[i] + kt, &sB0[(i * 256 + wave * 64) * 8]);
      gl2lds16(gb1[i] + kt, &sB1[(i * 256 + wave * 64) * 8]);
    }
    __syncthreads();
#pragma unroll
    for (int ks = 0; ks < 2; ++ks) {
      const int ko = ks * 32 + (lane >> 4) * 8;
      bf16x8_t af[4], b0f[2], b1f[2];
#pragma unroll
      for (int mi = 0; mi < 4; ++mi)
        af[mi] = *(const bf16x8_t*)&sA[(wm * 64 + mi * 16 + (lane & 15)) * 64 + ko];
#pragma unroll
      for (int ni = 0; ni < 2; ++ni) {
        b0f[ni] = *(const bf16x8_t*)&sB0[(wn * 32 + ni * 16 + (lane & 15)) * 64 + ko];
        b1f[ni] = *(const bf16x8_t*)&sB1[(wn * 32 + ni * 16 + (lane & 15)) * 64 + ko];
      }
#pragma unroll
      for (int mi = 0; mi < 4; ++mi)
#pragma unroll
        for (int ni = 0; ni < 2; ++ni) {
          accg[mi][ni] = __builtin_amdgcn_mfma_f32_16x16x32_bf16(
              af[mi], b0f[ni], accg[mi][ni], 0, 0, 0);
          accu[mi][ni] = __builtin_amdgcn_mfma_f32_16x16x32_bf16(
              af[mi], b1f[ni], accu[mi][ni], 0, 0, 0);
        }
    }
    __syncthreads();
  }

  // epilogue: h = silu(g)*u, bf16.  C/D layout: col=lane&15, row=quad*4+r.
  const int col = lane & 15;
#pragma unroll
  for (int mi = 0; mi < 4; ++mi) {
    const long mrow = m0 + wm * 64 + mi * 16 + (lane >> 4) * 4;
#pragma unroll
    for (int ni = 0; ni < 2; ++ni) {
      const long ncol = n0 + wn * 32 + ni * 16 + col;
#pragma unroll
      for (int r = 0; r < 4; ++r) {
        const float g = accg[mi][ni][r];
        const float u = accu[mi][ni][r];
        const float sg = g / (1.0f + __expf(-g));
        h[(mrow + r) * I_DIM + ncol] = f2bf(sg * u);
      }
    }
  }
}

// ---------------------------------------------------------------------------
// Kernel 4: down-proj GEMM (m97 replica).  out = h @ W2, fp32 out.
// BM=128, BN=128, BK=64, 256 threads, 2x2 waves each 64x64 (4x4 frags).
// ---------------------------------------------------------------------------
__global__ __launch_bounds__(256) void k_gemm2(
    const unsigned short* __restrict__ a,    // h   [M][I] bf16
    const unsigned short* __restrict__ bt,   // w2t [H][I] bf16 (N-major)
    float* __restrict__ out) {               // [M][H] fp32
  __shared__ __align__(16) unsigned short sA[128 * 64];
  __shared__ __align__(16) unsigned short sB[128 * 64];

  const int Ntiles = H_DIM / 128;  // 32
  const int GROUP = 32;
  const int id = blockIdx.x;
  const int group = id / (GROUP * Ntiles);
  const int local = id - group * (GROUP * Ntiles);
  const int nt = local / GROUP;
  const int mt = group * GROUP + (local - nt * GROUP);
  const long m0 = (long)mt * 128;
  const long n0 = (long)nt * 128;

  const int t = threadIdx.x;
  const int lane = t & 63;
  const int wave = t >> 6;
  const int wm = wave >> 1;
  const int wn = wave & 1;

  f32x4_t acc[4][4];
  const f32x4_t fzero = {0.f, 0.f, 0.f, 0.f};
#pragma unroll
  for (int mi = 0; mi < 4; ++mi)
#pragma unroll
    for (int ni = 0; ni < 4; ++ni) acc[mi][ni] = fzero;

  const unsigned short* ga[4];
  const unsigned short* gb[4];
#pragma unroll
  for (int i = 0; i < 4; ++i) {
    const int c = i * 256 + wave * 64 + lane;
    ga[i] = a + (m0 + (c >> 3)) * I_DIM + ((c & 7) << 3);
    gb[i] = bt + (n0 + (c >> 3)) * I_DIM + ((c & 7) << 3);
  }

  for (int kt = 0; kt < I_DIM; kt += 64) {
#pragma unroll
    for (int i = 0; i < 4; ++i) {
      gl2lds16(ga[i] + kt, &sA[(i * 256 + wave * 64) * 8]);
      gl2lds16(gb[i] + kt, &sB[(i * 256 + wave * 64) * 8]);
    }
    __syncthreads();
#pragma unroll
    for (int ks = 0; ks < 2; ++ks) {
      const int ko = ks * 32 + (lane >> 4) * 8;
      bf16x8_t af[4], bfr[4];
#pragma unroll
      for (int mi = 0; mi < 4; ++mi)
        af[mi] = *(const bf16x8_t*)&sA[(wm * 64 + mi * 16 + (lane & 15)) * 64 + ko];
#pragma unroll
      for (int ni = 0; ni < 4; ++ni)
        bfr[ni] = *(const bf16x8_t*)&sB[(wn * 64 + ni * 16 + (lane & 15)) * 64 + ko];
#pragma unroll
      for (int mi = 0; mi < 4; ++mi)
#pragma unroll
        for (int ni = 0; ni < 4; ++ni)
          acc[mi][ni] = __builtin_amdgcn_mfma_f32_16x16x32_bf16(
              af[mi], bfr[ni], acc[mi][ni], 0, 0, 0);
    }
    __syncthreads();
  }

  const int col = lane & 15;
#pragma unroll
  for (int mi = 0; mi < 4; ++mi) {
    const long mrow = m0 + wm * 64 + mi * 16 + (lane >> 4) * 4;
#pragma unroll
    for (int ni = 0; ni < 4; ++ni) {
      const long ncol = n0 + wn * 64 + ni * 16 + col;
#pragma unroll
      for (int r = 0; r < 4; ++r)
        out[(mrow + r) * H_DIM + ncol] = acc[mi][ni][r];
    }
  }
}

// ---------------------------------------------------------------------------
// Launch.  ws layout (peak exactly 512 MiB):
//   xb  [M][H]   bf16   @ 0          ( 64 MiB)
//   w0t [I][H]   bf16   @ 64 MiB     (112 MiB)  <- w2t [H][I] aliases this after gemm1
//   w1t [I][H]   bf16   @ 176 MiB    (112 MiB)
//   h   [M][I]   bf16   @ 288 MiB    (224 MiB)
// ---------------------------------------------------------------------------
extern "C" void kernel_launch(void* const* d_in, const int* in_sizes, int n_in,
                              void* d_out, int out_size, void* d_ws, size_t ws_size,
                              hipStream_t stream) {
  const float* x  = (const float*)d_in[0];
  const int* w0   = (const int*)d_in[1];
  const int* w1   = (const int*)d_in[2];
  const int* w2   = (const int*)d_in[3];
  const float* s0 = (const float*)d_in[4];
  const float* s1 = (const float*)d_in[5];
  const float* s2 = (const float*)d_in[6];
  float* out = (float*)d_out;

  char* p = (char*)d_ws;
  unsigned short* xb  = (unsigned short*)p;                 // M*H
  unsigned short* w0t = (unsigned short*)(p + (long)M_TOT * H_DIM * 2);
  unsigned short* w1t = (unsigned short*)(p + (long)M_TOT * H_DIM * 2 +
                                          (long)I_DIM * H_DIM * 2);
  unsigned short* hb  = (unsigned short*)(p + (long)M_TOT * H_DIM * 2 +
                                          2 * (long)I_DIM * H_DIM * 2);
  unsigned short* w2t = w0t;  // reuse after gemm1 has consumed w0t

  k_cvt_x<<<8192, 256, 0, stream>>>(x, xb, (long)M_TOT * H_DIM / 4);

  k_dequant_t<<<dim3(I_DIM / 64, H_DIM / 64), 256, 0, stream>>>(
      w0, s0, w0t, H_DIM, I_DIM);
  k_dequant_t<<<dim3(I_DIM / 64, H_DIM / 64), 256, 0, stream>>>(
      w1, s1, w1t, H_DIM, I_DIM);

  k_gemm1<<<(M_TOT / 128) * (I_DIM / 64), 256, 0, stream>>>(xb, w0t, w1t, hb);

  k_dequant_t<<<dim3(H_DIM / 64, I_DIM / 64), 256, 0, stream>>>(
      w2, s2, w2t, I_DIM, H_DIM);

  k_gemm2<<<(M_TOT / 128) * (H_DIM / 128), 256, 0, stream>>>(hb, w2t, out);
}